// Round 3
// baseline (1912.025 us; speedup 1.0000x reference)
//
#include <hip/hip_runtime.h>

// GC_LSTM: B=32, T=16, N=2048, HID=32.
// Key structural facts exploited:
//  - A_q/A_h/A are unused by the reference (ChebConv K=1 == Linear).
//  - x is only read at t=0; afterwards the scalar prediction is fed back.
//  - Nodes (B*N = 65536) are fully independent -> 1 thread per node,
//    sequential T loop in-thread, state in registers.
//  - All weight indices are wave-uniform + compile-time constant -> the
//    compiler emits s_load (SMEM pipe, scalar cache broadcast); VALU does
//    pure v_fma_f32 with one SGPR operand each.

#define B_ 32
#define T_ 16
#define N_ 2048
#define H_ 32

__device__ __forceinline__ float fast_rcp(float x) {
    return __builtin_amdgcn_rcpf(x);
}

__device__ __forceinline__ float sigmoid_f(float x) {
    // 1 / (1 + e^-x); rcp approx (~1ulp) + fast exp, plenty for 1.4e-3 abs tol
    return fast_rcp(1.0f + __expf(-x));
}

__device__ __forceinline__ float tanh_f(float x) {
    // tanh(x) = 1 - 2/(exp(2x)+1); saturates correctly at +/-inf
    return fmaf(-2.0f, fast_rcp(1.0f + __expf(2.0f * x)), 1.0f);
}

__global__ __launch_bounds__(256, 1) void gclstm_kernel(
    const float* __restrict__ x,      // [B,T,N]
    const float* __restrict__ W_in,   // [32,1]
    const float* __restrict__ b_in,   // [32]
    const float* __restrict__ W_gc,   // [32,32]
    const float* __restrict__ b_gc,   // [32]
    const float* __restrict__ W_x2h,  // [128,64]
    const float* __restrict__ b_x2h,  // [128]
    const float* __restrict__ W_h2h,  // [128,32]
    const float* __restrict__ b_h2h,  // [128]
    const float* __restrict__ W_out,  // [1,32]
    const float* __restrict__ b_out,  // [1]
    float* __restrict__ out)          // [B,T,N]
{
    const int tid = blockIdx.x * 256 + threadIdx.x;   // node id in [0, B*N)
    const int b = tid >> 11;    // / N_
    const int n = tid & (N_ - 1);

    float h[H_], c[H_];
#pragma unroll
    for (int k = 0; k < H_; ++k) { h[k] = 0.0f; c[k] = 0.0f; }

    // x[b, 0, n] — only element of x ever used
    float xn = x[b * (T_ * N_) + n];

    float* outp = out + b * (T_ * N_) + n;

#pragma unroll 1
    for (int t = 0; t < T_; ++t) {
        // ---- fc_in + relu: xf[k] = relu(xn * W_in[k] + b_in[k]) ----
        float xf[H_];
#pragma unroll
        for (int k = 0; k < H_; ++k) {
            float v = fmaf(xn, W_in[k], b_in[k]);
            xf[k] = fmaxf(v, 0.0f);
        }

        // ---- ChebConv K=1 == Linear(32,32) + relu ----
        float xg[H_];
#pragma unroll
        for (int k = 0; k < H_; ++k) {
            float acc = b_gc[k];
#pragma unroll
            for (int j = 0; j < H_; ++j)
                acc = fmaf(xf[j], W_gc[k * H_ + j], acc);
            xg[k] = fmaxf(acc, 0.0f);
        }

        // ---- LSTM gates + cell update ----
        // gates[k] = xc @ W_x2h.T + b_x2h + h @ W_h2h.T + b_h2h
        // xc = [xf | xg]; i=gates[0:32], f=[32:64], g=[64:96], o=[96:128]
        float hy[H_];
#pragma unroll
        for (int k = 0; k < H_; ++k) {
            float gi = b_x2h[k]      + b_h2h[k];
            float gf = b_x2h[32 + k] + b_h2h[32 + k];
            float gg = b_x2h[64 + k] + b_h2h[64 + k];
            float go = b_x2h[96 + k] + b_h2h[96 + k];
#pragma unroll
            for (int j = 0; j < H_; ++j) {
                const float v = xf[j];
                gi = fmaf(v, W_x2h[(0  + k) * 64 + j], gi);
                gf = fmaf(v, W_x2h[(32 + k) * 64 + j], gf);
                gg = fmaf(v, W_x2h[(64 + k) * 64 + j], gg);
                go = fmaf(v, W_x2h[(96 + k) * 64 + j], go);
            }
#pragma unroll
            for (int j = 0; j < H_; ++j) {
                const float v = xg[j];
                gi = fmaf(v, W_x2h[(0  + k) * 64 + 32 + j], gi);
                gf = fmaf(v, W_x2h[(32 + k) * 64 + 32 + j], gf);
                gg = fmaf(v, W_x2h[(64 + k) * 64 + 32 + j], gg);
                go = fmaf(v, W_x2h[(96 + k) * 64 + 32 + j], go);
            }
#pragma unroll
            for (int j = 0; j < H_; ++j) {
                const float v = h[j];
                gi = fmaf(v, W_h2h[(0  + k) * 32 + j], gi);
                gf = fmaf(v, W_h2h[(32 + k) * 32 + j], gf);
                gg = fmaf(v, W_h2h[(64 + k) * 32 + j], gg);
                go = fmaf(v, W_h2h[(96 + k) * 32 + j], go);
            }
            const float cy = fmaf(c[k], sigmoid_f(gf), sigmoid_f(gi) * tanh_f(gg));
            c[k] = cy;
            hy[k] = sigmoid_f(go) * tanh_f(cy);
        }

        // ---- fc_out + state rotate ----
        float acc = b_out[0];
#pragma unroll
        for (int k = 0; k < H_; ++k) {
            acc = fmaf(hy[k], W_out[k], acc);
            h[k] = hy[k];
        }
        xn = acc;
        outp[t * N_] = xn;   // out[b, t, n] — coalesced across n
    }
}

extern "C" void kernel_launch(void* const* d_in, const int* in_sizes, int n_in,
                              void* d_out, int out_size, void* d_ws, size_t ws_size,
                              hipStream_t stream) {
    // setup_inputs() order:
    // 0:x 1:A_q 2:A_h 3:A 4:W_in 5:b_in 6:W_gc 7:b_gc
    // 8:W_x2h 9:b_x2h 10:W_h2h 11:b_h2h 12:W_out 13:b_out
    const float* x     = (const float*)d_in[0];
    const float* W_in  = (const float*)d_in[4];
    const float* b_in  = (const float*)d_in[5];
    const float* W_gc  = (const float*)d_in[6];
    const float* b_gc  = (const float*)d_in[7];
    const float* W_x2h = (const float*)d_in[8];
    const float* b_x2h = (const float*)d_in[9];
    const float* W_h2h = (const float*)d_in[10];
    const float* b_h2h = (const float*)d_in[11];
    const float* W_out = (const float*)d_in[12];
    const float* b_out = (const float*)d_in[13];
    float* out = (float*)d_out;

    const int total = B_ * N_;              // 65536 nodes
    dim3 block(256);
    dim3 grid(total / 256);                 // 256 blocks -> 1 per CU

    gclstm_kernel<<<grid, block, 0, stream>>>(
        x, W_in, b_in, W_gc, b_gc, W_x2h, b_x2h, W_h2h, b_h2h,
        W_out, b_out, out);
}

// Round 7
// 1314.953 us; speedup vs baseline: 1.4541x; 1.4541x over previous
//
#include <hip/hip_runtime.h>

// GC_LSTM: B=32, T=16, N=2048, HID=32. Round 2 of optimization.
//
// R0 result: 1912us, VALUBusy 23%, 1 wave/SIMD (grid-limited), latency-bound
// on the wave-uniform s_load weight stream (~53KB/step through ~112 SGPRs).
//
// Fix: split each node's 32 channels across the 4 WAVES of a block
// (not across lanes -- lanes keep wave-uniform weight indices so weights
// stay on the scalar/SMEM path). 4x waves (4/SIMD), 1/4 the weight
// stream per wave, cross-slice exchange via LDS + 3 barriers/step.
//
//   block = 256 thr = 4 waves; wave w owns channels [8w, 8w+8); lane = node.
//   grid  = 1024 blocks = 64 nodes/block = exactly 4 blocks/CU.
//
// Per step: A) xn = b_out + sum of 4 per-wave fc_out partials (LDS)
//           B) xf slice -> LDS | bar1 | D) read xf[32]
//           E) xg slice -> LDS   F) gates += xf part   G) gates += h part (read HY)
//           bar2 | I) gates += xg part  J) nonlin, c/hy update, fc_out partial
//           bar3
// Register lifetimes kept disjoint (xf dies before h loads, h before xg) ->
// peak ~90 VGPR, fits __launch_bounds__(256,4)'s 128-VGPR cap.

#define B_ 32
#define T_ 16
#define N_ 2048
#define H_ 32
#define NPB 64   // nodes per block (= lanes)
#define WPB 4    // waves per block
#define KPW 8    // channels per wave

__device__ __forceinline__ float fast_rcp(float x) { return __builtin_amdgcn_rcpf(x); }
__device__ __forceinline__ float sigmoid_f(float x) { return fast_rcp(1.0f + __expf(-x)); }
__device__ __forceinline__ float tanh_f(float x) {
    return fmaf(-2.0f, fast_rcp(1.0f + __expf(2.0f * x)), 1.0f);
}

__global__ __launch_bounds__(256, 4) void gclstm_kernel(
    const float* __restrict__ x,      // [B,T,N]
    const float* __restrict__ W_in,   // [32,1]
    const float* __restrict__ b_in,   // [32]
    const float* __restrict__ W_gc,   // [32,32]
    const float* __restrict__ b_gc,   // [32]
    const float* __restrict__ W_x2h,  // [128,64]
    const float* __restrict__ b_x2h,  // [128]
    const float* __restrict__ W_h2h,  // [128,32]
    const float* __restrict__ b_h2h,  // [128]
    const float* __restrict__ W_out,  // [1,32]
    const float* __restrict__ b_out,  // [1]
    float* __restrict__ out)          // [B,T,N]
{
    __shared__ float XF[H_][NPB];     // 8KB  xf exchange
    __shared__ float XG[H_][NPB];     // 8KB  xg exchange
    __shared__ float HY[H_][NPB];     // 8KB  hy/h exchange
    __shared__ float PART[WPB][NPB];  // 1KB  fc_out partials

    const int lane = threadIdx.x & 63;
    // readfirstlane: wid IS wave-uniform; force it into an SGPR so every
    // weight index is provably uniform -> s_load, not per-lane vector loads.
    const int wid = __builtin_amdgcn_readfirstlane(threadIdx.x >> 6);
    const int node = blockIdx.x * NPB + lane;
    const int b = node >> 11;          // / N_
    const int n = node & (N_ - 1);

    // init exchange buffers (h(0) = 0, no partials yet)
#pragma unroll
    for (int k = 0; k < KPW; ++k) HY[wid * KPW + k][lane] = 0.0f;
    PART[wid][lane] = 0.0f;

    float c[KPW];
#pragma unroll
    for (int k = 0; k < KPW; ++k) c[k] = 0.0f;

    const float x0 = x[b * (T_ * N_) + n];   // only element of x ever used
    float* outp = out + b * (T_ * N_) + n;
    const float bo = b_out[0];

    __syncthreads();

#pragma unroll 1
    for (int t = 0; t < T_; ++t) {
        // ---- A: xn = fc_out(h(t)) from per-wave partials; also IS out[t-1] ----
        float xn = bo + PART[0][lane] + PART[1][lane] + PART[2][lane] + PART[3][lane];
        if (t == 0) {
            xn = x0;
        } else if (wid == 0) {
            outp[(t - 1) * N_] = xn;    // coalesced across lanes (n contiguous)
        }

        // ---- B: fc_in + relu, this wave's 8 channels ----
#pragma unroll
        for (int k = 0; k < KPW; ++k) {
            const int ch = wid * KPW + k;
            XF[ch][lane] = fmaxf(fmaf(xn, W_in[ch], b_in[ch]), 0.0f);
        }
        __syncthreads();   // bar1: XF complete

        // ---- D: gather full xf[32] ----
        float xf[H_];
#pragma unroll
        for (int j = 0; j < H_; ++j) xf[j] = XF[j][lane];

        // ---- E: ChebConv(K=1)+relu, this wave's 8 channels ----
#pragma unroll
        for (int k = 0; k < KPW; ++k) {
            const int ch = wid * KPW + k;
            float acc = b_gc[ch];
#pragma unroll
            for (int j = 0; j < H_; ++j) acc = fmaf(xf[j], W_gc[ch * H_ + j], acc);
            XG[ch][lane] = fmaxf(acc, 0.0f);
        }

        // ---- F: gate accumulation over xf (xc[0:32]) ----
        float gi[KPW], gf[KPW], gg[KPW], go[KPW];
#pragma unroll
        for (int k = 0; k < KPW; ++k) {
            const int ch = wid * KPW + k;
            float ai = b_x2h[ch]      + b_h2h[ch];
            float af = b_x2h[32 + ch] + b_h2h[32 + ch];
            float ag = b_x2h[64 + ch] + b_h2h[64 + ch];
            float ao = b_x2h[96 + ch] + b_h2h[96 + ch];
#pragma unroll
            for (int j = 0; j < H_; ++j) {
                const float v = xf[j];
                ai = fmaf(v, W_x2h[(ch     ) * 64 + j], ai);
                af = fmaf(v, W_x2h[(ch + 32) * 64 + j], af);
                ag = fmaf(v, W_x2h[(ch + 64) * 64 + j], ag);
                ao = fmaf(v, W_x2h[(ch + 96) * 64 + j], ao);
            }
            gi[k] = ai; gf[k] = af; gg[k] = ag; go[k] = ao;
        }
        // xf dead here

        // ---- G: gate accumulation over h(t) (read HY, written last step) ----
        {
            float h[H_];
#pragma unroll
            for (int j = 0; j < H_; ++j) h[j] = HY[j][lane];
#pragma unroll
            for (int k = 0; k < KPW; ++k) {
                const int ch = wid * KPW + k;
                float ai = gi[k], af = gf[k], ag = gg[k], ao = go[k];
#pragma unroll
                for (int j = 0; j < H_; ++j) {
                    const float v = h[j];
                    ai = fmaf(v, W_h2h[(ch     ) * H_ + j], ai);
                    af = fmaf(v, W_h2h[(ch + 32) * H_ + j], af);
                    ag = fmaf(v, W_h2h[(ch + 64) * H_ + j], ag);
                    ao = fmaf(v, W_h2h[(ch + 96) * H_ + j], ao);
                }
                gi[k] = ai; gf[k] = af; gg[k] = ag; go[k] = ao;
            }
        }
        __syncthreads();   // bar2: XG complete (and all G-reads of HY done)

        // ---- I: gate accumulation over xg (xc[32:64]) ----
        {
            float xg[H_];
#pragma unroll
            for (int j = 0; j < H_; ++j) xg[j] = XG[j][lane];
#pragma unroll
            for (int k = 0; k < KPW; ++k) {
                const int ch = wid * KPW + k;
                float ai = gi[k], af = gf[k], ag = gg[k], ao = go[k];
#pragma unroll
                for (int j = 0; j < H_; ++j) {
                    const float v = xg[j];
                    ai = fmaf(v, W_x2h[(ch     ) * 64 + 32 + j], ai);
                    af = fmaf(v, W_x2h[(ch + 32) * 64 + 32 + j], af);
                    ag = fmaf(v, W_x2h[(ch + 64) * 64 + 32 + j], ag);
                    ao = fmaf(v, W_x2h[(ch + 96) * 64 + 32 + j], ao);
                }
                gi[k] = ai; gf[k] = af; gg[k] = ag; go[k] = ao;
            }
        }

        // ---- J: nonlinearity, cell update, hy -> LDS, fc_out partial ----
        float part = 0.0f;
#pragma unroll
        for (int k = 0; k < KPW; ++k) {
            const int ch = wid * KPW + k;
            const float cy = fmaf(c[k], sigmoid_f(gf[k]), sigmoid_f(gi[k]) * tanh_f(gg[k]));
            c[k] = cy;
            const float hyv = sigmoid_f(go[k]) * tanh_f(cy);
            HY[ch][lane] = hyv;
            part = fmaf(hyv, W_out[ch], part);
        }
        PART[wid][lane] = part;
        __syncthreads();   // bar3: HY/PART complete -> next step
    }

    // ---- epilogue: out[T-1] = fc_out(hy(T-1)) ----
    if (wid == 0) {
        float xn = bo + PART[0][lane] + PART[1][lane] + PART[2][lane] + PART[3][lane];
        outp[(T_ - 1) * N_] = xn;
    }
}

extern "C" void kernel_launch(void* const* d_in, const int* in_sizes, int n_in,
                              void* d_out, int out_size, void* d_ws, size_t ws_size,
                              hipStream_t stream) {
    // setup_inputs() order:
    // 0:x 1:A_q 2:A_h 3:A 4:W_in 5:b_in 6:W_gc 7:b_gc
    // 8:W_x2h 9:b_x2h 10:W_h2h 11:b_h2h 12:W_out 13:b_out
    const float* x     = (const float*)d_in[0];
    const float* W_in  = (const float*)d_in[4];
    const float* b_in  = (const float*)d_in[5];
    const float* W_gc  = (const float*)d_in[6];
    const float* b_gc  = (const float*)d_in[7];
    const float* W_x2h = (const float*)d_in[8];
    const float* b_x2h = (const float*)d_in[9];
    const float* W_h2h = (const float*)d_in[10];
    const float* b_h2h = (const float*)d_in[11];
    const float* W_out = (const float*)d_in[12];
    const float* b_out = (const float*)d_in[13];
    float* out = (float*)d_out;

    dim3 block(256);                       // 4 waves
    dim3 grid((B_ * N_) / NPB);            // 1024 blocks = 4 per CU

    gclstm_kernel<<<grid, block, 0, stream>>>(
        x, W_in, b_in, W_gc, b_gc, W_x2h, b_x2h, W_h2h, b_h2h,
        W_out, b_out, out);
}